// Round 9
// baseline (92.106 us; speedup 1.0000x reference)
//
#include <hip/hip_runtime.h>

// MinEuclideanDistBlock: out[b,n] = min_w sum_c sqrt(max(||win||^2 + ||shp||^2 - 2*cross, 0))
// B=64, C=3, L=2048, N=256, S=64, W=1985.
// v10 = v4 skeleton + cross-iteration A-fragment prefetch pipeline (T14).
//   Iteration it issues it+1's ds_reads into explicit 'next' registers BEFORE
//   running it's sqrt/min epilogue -> LDS latency hides under epilogue VALU.
//   (v6's intra-phase 2-stream failed: compiler kept VGPR=64 and serialized;
//   explicit cross-iteration regs force the overlap. Watch VGPR_Count ~100-120.)
//   'continue' removed so the pipeline never breaks: tail its compute garbage,
//   masked fold drops them (fmaxf(NaN,0)=0 keeps lanes finite).
//   Kept from v4 (verified): grid 512 = 64b x 2nh x 4wq, 512 thr, 16w x 32n tile,
//   4-copy skewed conflict-free xls, -2x pre-scale, f32 wsq, fused 3-sqrt epilogue,
//   atomicMin merge (nonneg float-as-uint), 0x7f memset. No setprio (null, m190).

typedef float  v4f __attribute__((ext_vector_type(4)));
typedef short  v8s __attribute__((ext_vector_type(8)));
typedef unsigned short u16;
typedef unsigned int   u32;
typedef unsigned long long u64;

#define S_ 64
#define N_ 256
#define C_ 3
#define B_ 64
#define L_ 2048
#define W_ 1985
#define WQL 512            // windows per w-quarter block
#define NC 146             // u64 chunks staged per shifted copy (584 els >= 512+63)
#define CSTRIDE 160        // u64 stride per copy (incl. 4r skew; 320 dwords == 0 mod 32)
#define THREADS 512

__device__ __forceinline__ u16 f2bf(float f) {
    u32 u = __builtin_bit_cast(u32, f);
    return (u16)((u + 0x7FFFu + ((u >> 16) & 1u)) >> 16);
}
__device__ __forceinline__ float bf2f(u16 b) {
    return __builtin_bit_cast(float, ((u32)b) << 16);
}

__global__ __launch_bounds__(THREADS, 4)
void shapelet_min_kernel(const float* __restrict__ x,
                         const float* __restrict__ shp,
                         float* __restrict__ out)
{
    __shared__ u64   xls[C_ * 4 * CSTRIDE];  // 15360 B: 4 skewed shifted bf16 copies of -2*x
    __shared__ float wsq[C_][WQL];           // 6144 B : window sq-norms (f32)
    __shared__ u16   scratch[C_ * 64 * 72];  // 27648 B: shapelet tile (row stride 72)
    __shared__ float red[8][64];             // 2048 B : cross-wave min reduction

    const int tid  = threadIdx.x;
    const int wave = tid >> 6;
    const int lane = tid & 63;
    const int m    = lane & 15;      // MFMA row/col within 16
    const int q    = lane >> 4;      // quad id 0..3
    const int ww   = wave & 3;       // w-group 0..3 (16 windows each per iter)
    const int wn   = wave >> 2;      // n-group 0..1 (32 shapelets each)
    const int blk  = blockIdx.x;
    const int wq   = blk & 3;
    const int nh   = (blk >> 2) & 1;
    const int b    = blk >> 3;
    const int w0   = wq << 9;                        // quarter base window
    const int wlen = min(WQL, W_ - w0);              // 512,512,512,449

    //=== Issue x global loads early (quarter [w0, w0+584) of each channel) ===
    const float* xb = x + (size_t)b * (C_ * L_);
    float xf[8];
    int xc = 0, xt = 0;
    bool xact = (tid < C_ * NC);                     // 438 active
    if (xact) {
        xc = tid / NC;
        xt = tid - xc * NC;
        int e = w0 + (xt << 2);
        if (e + 7 < L_) {
            v4f a0 = *(const v4f*)(xb + xc * L_ + e);
            v4f a1 = *(const v4f*)(xb + xc * L_ + e + 4);
            xf[0] = a0[0]; xf[1] = a0[1]; xf[2] = a0[2]; xf[3] = a0[3];
            xf[4] = a1[0]; xf[5] = a1[1]; xf[6] = a1[2]; xf[7] = a1[3];
        } else {
            #pragma unroll
            for (int i = 0; i < 8; ++i)
                xf[i] = (e + i < L_) ? xb[xc * L_ + e + i] : 0.f;
        }
    }

    //=== Stage shapelet tile for n-group g=0 (overlaps x-load latency) ===
    const int nbase = nh << 7;                       // 128-sized n-half
    #pragma unroll
    for (int k = 0; k < 6; ++k) {
        int idx = tid + k * THREADS;                 // 3072 float4-groups: (c, n, sq)
        int sq = idx & 15;
        int n  = (idx >> 4) & 63;
        int c  = idx >> 10;
        v4f v = *(const v4f*)(shp + ((size_t)(c * N_ + nbase + n) * S_ + (sq << 2)));
        u64 pk = (u64)f2bf(v[0]) | ((u64)f2bf(v[1]) << 16)
               | ((u64)f2bf(v[2]) << 32) | ((u64)f2bf(v[3]) << 48);
        *(u64*)(scratch + ((c * 64 + n) * 72 + (sq << 2))) = pk;
    }

    //=== Write 4 skewed shifted bf16 copies of -2*x (whole aligned u64 chunks) ===
    if (xact) {
        u16 w8[8];
        #pragma unroll
        for (int i = 0; i < 8; ++i) w8[i] = f2bf(-2.f * xf[i]);
        #pragma unroll
        for (int r = 0; r < 4; ++r) {                // copy r chunk t = elements 4t+r..4t+r+3
            u64 pk = (u64)w8[r] | ((u64)w8[r + 1] << 16)
                   | ((u64)w8[r + 2] << 32) | ((u64)w8[r + 3] << 48);
            xls[(xc * 4 + r) * CSTRIDE + 4 * r + xt] = pk;
        }
    }
    __syncthreads();

    //=== wsq: rolling sliding sum of squares from copy 0 (values -2x -> *0.25), f32 ===
    if (tid < 128 * C_) {                            // 384 units: (c, 4-window group)
        int c  = tid >> 7;
        int t0 = tid & 127;                          // window base = 4*t0
        const u64* cp0 = &xls[(c * 4) * CSTRIDE];
        u64 ch = cp0[t0];
        float h0 = bf2f((u16)ch),         h1 = bf2f((u16)(ch >> 16)),
              h2 = bf2f((u16)(ch >> 32)), h3 = bf2f((u16)(ch >> 48));
        float sq0 = h0 * h0, sq1 = h1 * h1, sq2 = h2 * h2;
        float s = sq0 + sq1 + sq2 + h3 * h3;
        #pragma unroll
        for (int kk = 1; kk < 16; ++kk) {
            u64 c2 = cp0[t0 + kk];
            float e0 = bf2f((u16)c2),         e1 = bf2f((u16)(c2 >> 16)),
                  e2 = bf2f((u16)(c2 >> 32)), e3 = bf2f((u16)(c2 >> 48));
            s += e0 * e0; s += e1 * e1; s += e2 * e2; s += e3 * e3;
        }
        u64 ct = cp0[t0 + 16];
        float t4 = bf2f((u16)ct), t5 = bf2f((u16)(ct >> 16)), t6 = bf2f((u16)(ct >> 32));
        float s0 = s;
        float s1 = s0 - sq0 + t4 * t4;
        float s2 = s1 - sq1 + t5 * t5;
        float s3 = s2 - sq2 + t6 * t6;
        v4f o = (v4f){0.25f * s0, 0.25f * s1, 0.25f * s2, 0.25f * s3};
        *(v4f*)&wsq[c][t0 << 2] = o;
    }

    const int r  = m & 3;
    const int sE = m >> 2;
    const int Tq = 2 * q + sE;                       // lane part of chunk index

    //=== Two n-groups of 64; per group: B frags (nt=2), pipelined 8 w-iters ===
    #pragma unroll 1
    for (int g = 0; g < 2; ++g) {
        // B fragments (48 VGPR) + shapelet norms; scratch holds group g
        v8s bfr[C_][2][2];
        float ssq[C_][2];
        #pragma unroll
        for (int c = 0; c < C_; ++c) {
            #pragma unroll
            for (int nt = 0; nt < 2; ++nt) {
                float sacc = 0.f;
                #pragma unroll
                for (int h = 0; h < 2; ++h) {
                    v8s f = *(const v8s*)(scratch +
                             ((c * 64 + wn * 32 + nt * 16 + m) * 72 + h * 32 + q * 8));
                    bfr[c][nt][h] = f;
                    #pragma unroll
                    for (int j = 0; j < 8; ++j) {
                        float e = bf2f((u16)f[j]);
                        sacc += e * e;
                    }
                }
                sacc += __shfl_xor(sacc, 16);
                sacc += __shfl_xor(sacc, 32);
                ssq[c][nt] = sacc;                   // per-lane n = wn*32 + nt*16 + m
            }
        }
        __syncthreads();                             // wsq ready (g=0); red free (g=1)

        // pipeline prologue: prefetch A fragments for it=0
        v8s afc[C_][2];
        {
            const int T0 = ((ww * 16) >> 2) + Tq;
            #pragma unroll
            for (int c = 0; c < C_; ++c) {
                const u64* cp = &xls[(c * 4 + r) * CSTRIDE + 4 * r];
                union { u64 u[2]; v8s v; } a0, a1;
                a0.u[0] = cp[T0];     a0.u[1] = cp[T0 + 1];
                a1.u[0] = cp[T0 + 8]; a1.u[1] = cp[T0 + 9];
                afc[c][0] = a0.v; afc[c][1] = a1.v;
            }
        }

        float minv[2] = {1e30f, 1e30f};
        #pragma unroll 1
        for (int it = 0; it < 8; ++it) {
            const int wb  = it * 64 + ww * 16;
            const int wbn = (it < 7) ? wb + 64 : ww * 16;   // it=7: dummy (unused)

            // issue NEXT iteration's A-fragment reads (hide under this epilogue)
            v8s afn[C_][2];
            {
                const int Tn = (wbn >> 2) + Tq;
                #pragma unroll
                for (int c = 0; c < C_; ++c) {
                    const u64* cp = &xls[(c * 4 + r) * CSTRIDE + 4 * r];
                    union { u64 u[2]; v8s v; } a0, a1;
                    a0.u[0] = cp[Tn];     a0.u[1] = cp[Tn + 1];
                    a1.u[0] = cp[Tn + 8]; a1.u[1] = cp[Tn + 9];
                    afn[c][0] = a0.v; afn[c][1] = a1.v;
                }
            }

            // acc init = wsq(w) + ssq(n); MFMA adds -2*cross (A pre-scaled)
            v4f acc[C_][2];
            #pragma unroll
            for (int c = 0; c < C_; ++c) {
                v4f wv = *(const v4f*)&wsq[c][wb + (q << 2)];
                #pragma unroll
                for (int nt = 0; nt < 2; ++nt)
                    #pragma unroll
                    for (int gi = 0; gi < 4; ++gi)
                        acc[c][nt][gi] = wv[gi] + ssq[c][nt];
            }
            #pragma unroll
            for (int c = 0; c < C_; ++c)
                #pragma unroll
                for (int nt = 0; nt < 2; ++nt) {
                    acc[c][nt] = __builtin_amdgcn_mfma_f32_16x16x32_bf16(
                        afc[c][0], bfr[c][nt][0], acc[c][nt], 0, 0, 0);
                    acc[c][nt] = __builtin_amdgcn_mfma_f32_16x16x32_bf16(
                        afc[c][1], bfr[c][nt][1], acc[c][nt], 0, 0, 0);
                }

            // fused epilogue: t = sum_c sqrt(max(d2,0)); fold into running min
            if (wb + 16 <= wlen) {                   // wave-uniform fast path
                #pragma unroll
                for (int nt = 0; nt < 2; ++nt)
                    #pragma unroll
                    for (int gi = 0; gi < 4; ++gi) {
                        float t = __builtin_amdgcn_sqrtf(fmaxf(acc[0][nt][gi], 0.f))
                                + __builtin_amdgcn_sqrtf(fmaxf(acc[1][nt][gi], 0.f))
                                + __builtin_amdgcn_sqrtf(fmaxf(acc[2][nt][gi], 0.f));
                        minv[nt] = fminf(minv[nt], t);
                    }
            } else {                                 // tail / fully-invalid: masked
                #pragma unroll
                for (int nt = 0; nt < 2; ++nt)
                    #pragma unroll
                    for (int gi = 0; gi < 4; ++gi) {
                        float t = __builtin_amdgcn_sqrtf(fmaxf(acc[0][nt][gi], 0.f))
                                + __builtin_amdgcn_sqrtf(fmaxf(acc[1][nt][gi], 0.f))
                                + __builtin_amdgcn_sqrtf(fmaxf(acc[2][nt][gi], 0.f));
                        bool ok = (wb + (q << 2) + gi) < wlen;
                        minv[nt] = fminf(minv[nt], ok ? t : 1e30f);
                    }
            }

            // rotate pipeline registers
            #pragma unroll
            for (int c = 0; c < C_; ++c) {
                afc[c][0] = afn[c][0];
                afc[c][1] = afn[c][1];
            }
        }

        // quad reduce (same n across q)
        #pragma unroll
        for (int nt = 0; nt < 2; ++nt) {
            minv[nt] = fminf(minv[nt], __shfl_xor(minv[nt], 16));
            minv[nt] = fminf(minv[nt], __shfl_xor(minv[nt], 32));
        }

        // overlap: stage next n-group's shapelets while finishing this group's output
        if (g == 0) {
            #pragma unroll
            for (int k = 0; k < 6; ++k) {
                int idx = tid + k * THREADS;
                int sq = idx & 15;
                int n  = (idx >> 4) & 63;
                int c  = idx >> 10;
                v4f v = *(const v4f*)(shp +
                        ((size_t)(c * N_ + nbase + 64 + n) * S_ + (sq << 2)));
                u64 pk = (u64)f2bf(v[0]) | ((u64)f2bf(v[1]) << 16)
                       | ((u64)f2bf(v[2]) << 32) | ((u64)f2bf(v[3]) << 48);
                *(u64*)(scratch + ((c * 64 + n) * 72 + (sq << 2))) = pk;
            }
        }
        if (lane < 16) {
            red[wave][wn * 32 + lane]      = minv[0];
            red[wave][wn * 32 + 16 + lane] = minv[1];
        }
        __syncthreads();

        if (tid < 64) {
            int tn = tid >> 5;                       // which wn owns this n (wave = wn*4+ww)
            float v = red[tn * 4 + 0][tid];
            v = fminf(v, red[tn * 4 + 1][tid]);
            v = fminf(v, red[tn * 4 + 2][tid]);
            v = fminf(v, red[tn * 4 + 3][tid]);
            // nonneg floats order as uints -> atomicMin merges w-quarter partials
            atomicMin((u32*)out + ((size_t)b * N_ + nbase + (g << 6) + tid),
                      __float_as_uint(v));
        }
        // next g: scratch re-read (bfr load) happens after this barrier
        if (g == 0) __syncthreads();
    }
}

extern "C" void kernel_launch(void* const* d_in, const int* in_sizes, int n_in,
                              void* d_out, int out_size, void* d_ws, size_t ws_size,
                              hipStream_t stream) {
    const float* x   = (const float*)d_in[0];   // (64, 3, 2048) fp32
    const float* shp = (const float*)d_in[1];   // (3, 256, 64) fp32
    // init output to +huge (0x7f7f7f7f ~ 3.39e38) for atomicMin merging
    hipMemsetAsync(d_out, 0x7f, (size_t)B_ * N_ * sizeof(float), stream);
    hipLaunchKernelGGL(shapelet_min_kernel, dim3(512), dim3(THREADS), 0, stream,
                       x, shp, (float*)d_out);
}

// Round 10
// 85.495 us; speedup vs baseline: 1.0773x; 1.0773x over previous
//
#include <hip/hip_runtime.h>
#include <hip/hip_fp16.h>

// MinEuclideanDistBlock: out[b,n] = min_w sum_c sqrt(max(||win||^2 + ||shp||^2 - 2*cross, 0))
// B=64, C=3, L=2048, N=256, S=64, W=1985.
// FINAL (v11 = v4, the session's measured-best configuration, 85.1 us total):
//   grid 512 = 64b x 2 n-halves x 4 w-quarters; 512-thread blocks (8 waves:
//   4 w-groups x 2 n-groups), wave tile 16w x 32n (nt=2, bfr resident ~48 regs).
//   2 blocks/CU, 16 waves/CU. Skewed conflict-free shifted bf16 copies of -2*x
//   (copy r at +4r u64, stride 160 u64 == 0 mod 32 banks -> A-read bank =
//   8r+4q+2s, perfect b64 spread). Norms folded into MFMA acc-init; f32 wsq;
//   fused sqrt/sum/min epilogue; atomicMin merge (nonneg float-as-uint) with
//   0x7f memset init.
// Session ablation (v5-v10): occupancy, ILP, prologue-split, b128 A-reads,
//   norm-MFMA, SW-pipeline all neutral/negative -> this structure is the
//   practical plateau for plain-HIP on this op (~40 us kernel; wall is
//   distributed issue/latency stall, no single saturated pipe).

typedef float  v4f __attribute__((ext_vector_type(4)));
typedef short  v8s __attribute__((ext_vector_type(8)));
typedef unsigned short u16;
typedef unsigned int   u32;
typedef unsigned long long u64;

#define S_ 64
#define N_ 256
#define C_ 3
#define B_ 64
#define L_ 2048
#define W_ 1985
#define WQL 512            // windows per w-quarter block
#define NC 146             // u64 chunks staged per shifted copy (584 els >= 512+63)
#define CSTRIDE 160        // u64 stride per copy (incl. 4r skew; 320 dwords == 0 mod 32)
#define THREADS 512

__device__ __forceinline__ u16 f2bf(float f) {
    u32 u = __builtin_bit_cast(u32, f);
    return (u16)((u + 0x7FFFu + ((u >> 16) & 1u)) >> 16);
}
__device__ __forceinline__ float bf2f(u16 b) {
    return __builtin_bit_cast(float, ((u32)b) << 16);
}

__global__ __launch_bounds__(THREADS, 4)
void shapelet_min_kernel(const float* __restrict__ x,
                         const float* __restrict__ shp,
                         float* __restrict__ out)
{
    __shared__ u64   xls[C_ * 4 * CSTRIDE];  // 15360 B: 4 skewed shifted bf16 copies of -2*x
    __shared__ float wsq[C_][WQL];           // 6144 B : window sq-norms (f32)
    __shared__ u16   scratch[C_ * 64 * 72];  // 27648 B: shapelet tile (row stride 72 = 64+pad)
    __shared__ float red[8][64];             // 2048 B : cross-wave min reduction

    const int tid  = threadIdx.x;
    const int wave = tid >> 6;
    const int lane = tid & 63;
    const int m    = lane & 15;      // MFMA row/col within 16
    const int q    = lane >> 4;      // quad id 0..3
    const int ww   = wave & 3;       // w-group 0..3 (16 windows each per iter)
    const int wn   = wave >> 2;      // n-group 0..1 (32 shapelets each)
    const int blk  = blockIdx.x;
    const int wq   = blk & 3;
    const int nh   = (blk >> 2) & 1;
    const int b    = blk >> 3;
    const int w0   = wq << 9;                        // quarter base window
    const int wlen = min(WQL, W_ - w0);              // 512,512,512,449

    //=== Issue x global loads early (quarter [w0, w0+584) of each channel) ===
    const float* xb = x + (size_t)b * (C_ * L_);
    float xf[8];
    int xc = 0, xt = 0;
    bool xact = (tid < C_ * NC);                     // 438 active
    if (xact) {
        xc = tid / NC;
        xt = tid - xc * NC;
        int e = w0 + (xt << 2);
        if (e + 7 < L_) {
            v4f a0 = *(const v4f*)(xb + xc * L_ + e);
            v4f a1 = *(const v4f*)(xb + xc * L_ + e + 4);
            xf[0] = a0[0]; xf[1] = a0[1]; xf[2] = a0[2]; xf[3] = a0[3];
            xf[4] = a1[0]; xf[5] = a1[1]; xf[6] = a1[2]; xf[7] = a1[3];
        } else {
            #pragma unroll
            for (int i = 0; i < 8; ++i)
                xf[i] = (e + i < L_) ? xb[xc * L_ + e + i] : 0.f;
        }
    }

    //=== Stage shapelet tile for n-group g=0 (overlaps x-load latency) ===
    const int nbase = nh << 7;                       // 128-sized n-half
    #pragma unroll
    for (int k = 0; k < 6; ++k) {
        int idx = tid + k * THREADS;                 // 3072 float4-groups: (c, n, sq)
        int sq = idx & 15;
        int n  = (idx >> 4) & 63;
        int c  = idx >> 10;
        v4f v = *(const v4f*)(shp + ((size_t)(c * N_ + nbase + n) * S_ + (sq << 2)));
        u64 pk = (u64)f2bf(v[0]) | ((u64)f2bf(v[1]) << 16)
               | ((u64)f2bf(v[2]) << 32) | ((u64)f2bf(v[3]) << 48);
        *(u64*)(scratch + ((c * 64 + n) * 72 + (sq << 2))) = pk;
    }

    //=== Write 4 skewed shifted bf16 copies of -2*x (whole aligned u64 chunks) ===
    if (xact) {
        u16 w8[8];
        #pragma unroll
        for (int i = 0; i < 8; ++i) w8[i] = f2bf(-2.f * xf[i]);
        #pragma unroll
        for (int r = 0; r < 4; ++r) {                // copy r chunk t = elements 4t+r..4t+r+3
            u64 pk = (u64)w8[r] | ((u64)w8[r + 1] << 16)
                   | ((u64)w8[r + 2] << 32) | ((u64)w8[r + 3] << 48);
            xls[(xc * 4 + r) * CSTRIDE + 4 * r + xt] = pk;
        }
    }
    __syncthreads();

    //=== wsq: rolling sliding sum of squares from copy 0 (values -2x -> *0.25), f32 ===
    if (tid < 128 * C_) {                            // 384 units: (c, 4-window group)
        int c  = tid >> 7;
        int t0 = tid & 127;                          // window base = 4*t0
        const u64* cp0 = &xls[(c * 4) * CSTRIDE];
        u64 ch = cp0[t0];
        float h0 = bf2f((u16)ch),         h1 = bf2f((u16)(ch >> 16)),
              h2 = bf2f((u16)(ch >> 32)), h3 = bf2f((u16)(ch >> 48));
        float sq0 = h0 * h0, sq1 = h1 * h1, sq2 = h2 * h2;
        float s = sq0 + sq1 + sq2 + h3 * h3;
        #pragma unroll
        for (int kk = 1; kk < 16; ++kk) {
            u64 c2 = cp0[t0 + kk];
            float e0 = bf2f((u16)c2),         e1 = bf2f((u16)(c2 >> 16)),
                  e2 = bf2f((u16)(c2 >> 32)), e3 = bf2f((u16)(c2 >> 48));
            s += e0 * e0; s += e1 * e1; s += e2 * e2; s += e3 * e3;
        }
        u64 ct = cp0[t0 + 16];
        float t4 = bf2f((u16)ct), t5 = bf2f((u16)(ct >> 16)), t6 = bf2f((u16)(ct >> 32));
        float s0 = s;
        float s1 = s0 - sq0 + t4 * t4;
        float s2 = s1 - sq1 + t5 * t5;
        float s3 = s2 - sq2 + t6 * t6;
        v4f o = (v4f){0.25f * s0, 0.25f * s1, 0.25f * s2, 0.25f * s3};
        *(v4f*)&wsq[c][t0 << 2] = o;
    }

    const int r  = m & 3;
    const int sE = m >> 2;

    //=== Two n-groups of 64; per group: B frags (nt=2), 8 w-iters, reduce, atomicMin ===
    #pragma unroll 1
    for (int g = 0; g < 2; ++g) {
        // B fragments (48 VGPR) + shapelet norms; scratch holds group g
        v8s bfr[C_][2][2];
        float ssq[C_][2];
        #pragma unroll
        for (int c = 0; c < C_; ++c) {
            #pragma unroll
            for (int nt = 0; nt < 2; ++nt) {
                float sacc = 0.f;
                #pragma unroll
                for (int h = 0; h < 2; ++h) {
                    v8s f = *(const v8s*)(scratch +
                             ((c * 64 + wn * 32 + nt * 16 + m) * 72 + h * 32 + q * 8));
                    bfr[c][nt][h] = f;
                    #pragma unroll
                    for (int j = 0; j < 8; ++j) {
                        float e = bf2f((u16)f[j]);
                        sacc += e * e;
                    }
                }
                sacc += __shfl_xor(sacc, 16);
                sacc += __shfl_xor(sacc, 32);
                ssq[c][nt] = sacc;                   // per-lane n = wn*32 + nt*16 + m
            }
        }
        __syncthreads();                             // wsq ready (g=0); red free (g=1)

        float minv[2] = {1e30f, 1e30f};
        #pragma unroll 1
        for (int it = 0; it < 8; ++it) {
            const int wb = it * 64 + ww * 16;        // local window base for this wave
            if (wb >= wlen) continue;                // wave-uniform

            float sums[2][4];
            #pragma unroll
            for (int nt = 0; nt < 2; ++nt)
                #pragma unroll
                for (int gi = 0; gi < 4; ++gi) sums[nt][gi] = 0.f;

            #pragma unroll
            for (int c = 0; c < C_; ++c) {
                // A fragments: bank = 8r+4q+2s -> conflict-free b64 pairs
                const u64* cp = &xls[(c * 4 + r) * CSTRIDE + 4 * r];
                int T0 = (wb >> 2) + 2 * q + sE;
                union { u64 u[2]; v8s v; } a0, a1;
                a0.u[0] = cp[T0];     a0.u[1] = cp[T0 + 1];
                a1.u[0] = cp[T0 + 8]; a1.u[1] = cp[T0 + 9];

                // acc init = wsq(w) + ssq(n); MFMA adds -2*cross (A pre-scaled)
                v4f wv = *(const v4f*)&wsq[c][wb + (q << 2)];
                v4f acc[2];
                #pragma unroll
                for (int nt = 0; nt < 2; ++nt)
                    #pragma unroll
                    for (int gi = 0; gi < 4; ++gi)
                        acc[nt][gi] = wv[gi] + ssq[c][nt];
                #pragma unroll
                for (int nt = 0; nt < 2; ++nt) {
                    acc[nt] = __builtin_amdgcn_mfma_f32_16x16x32_bf16(a0.v, bfr[c][nt][0], acc[nt], 0, 0, 0);
                    acc[nt] = __builtin_amdgcn_mfma_f32_16x16x32_bf16(a1.v, bfr[c][nt][1], acc[nt], 0, 0, 0);
                }
                #pragma unroll
                for (int nt = 0; nt < 2; ++nt)
                    #pragma unroll
                    for (int gi = 0; gi < 4; ++gi)
                        sums[nt][gi] += __builtin_amdgcn_sqrtf(fmaxf(acc[nt][gi], 0.f));
            }
            if (wb + 16 <= wlen) {
                #pragma unroll
                for (int nt = 0; nt < 2; ++nt)
                    #pragma unroll
                    for (int gi = 0; gi < 4; ++gi)
                        minv[nt] = fminf(minv[nt], sums[nt][gi]);
            } else {
                #pragma unroll
                for (int gi = 0; gi < 4; ++gi) {
                    bool ok = (wb + (q << 2) + gi) < wlen;
                    #pragma unroll
                    for (int nt = 0; nt < 2; ++nt)
                        minv[nt] = fminf(minv[nt], ok ? sums[nt][gi] : 1e30f);
                }
            }
        }

        // quad reduce (same n across q)
        #pragma unroll
        for (int nt = 0; nt < 2; ++nt) {
            minv[nt] = fminf(minv[nt], __shfl_xor(minv[nt], 16));
            minv[nt] = fminf(minv[nt], __shfl_xor(minv[nt], 32));
        }

        // overlap: stage next n-group's shapelets while finishing this group's output
        if (g == 0) {
            #pragma unroll
            for (int k = 0; k < 6; ++k) {
                int idx = tid + k * THREADS;
                int sq = idx & 15;
                int n  = (idx >> 4) & 63;
                int c  = idx >> 10;
                v4f v = *(const v4f*)(shp +
                        ((size_t)(c * N_ + nbase + 64 + n) * S_ + (sq << 2)));
                u64 pk = (u64)f2bf(v[0]) | ((u64)f2bf(v[1]) << 16)
                       | ((u64)f2bf(v[2]) << 32) | ((u64)f2bf(v[3]) << 48);
                *(u64*)(scratch + ((c * 64 + n) * 72 + (sq << 2))) = pk;
            }
        }
        if (lane < 16) {
            red[wave][wn * 32 + lane]      = minv[0];
            red[wave][wn * 32 + 16 + lane] = minv[1];
        }
        __syncthreads();

        if (tid < 64) {
            int tn = tid >> 5;                       // which wn owns this n (wave = wn*4+ww)
            float v = red[tn * 4 + 0][tid];
            v = fminf(v, red[tn * 4 + 1][tid]);
            v = fminf(v, red[tn * 4 + 2][tid]);
            v = fminf(v, red[tn * 4 + 3][tid]);
            // nonneg floats order as uints -> atomicMin merges w-quarter partials
            atomicMin((u32*)out + ((size_t)b * N_ + nbase + (g << 6) + tid),
                      __float_as_uint(v));
        }
        // next g: scratch re-read (bfr load) happens after this barrier
        if (g == 0) __syncthreads();
    }
}

extern "C" void kernel_launch(void* const* d_in, const int* in_sizes, int n_in,
                              void* d_out, int out_size, void* d_ws, size_t ws_size,
                              hipStream_t stream) {
    const float* x   = (const float*)d_in[0];   // (64, 3, 2048) fp32
    const float* shp = (const float*)d_in[1];   // (3, 256, 64) fp32
    // init output to +huge (0x7f7f7f7f ~ 3.39e38) for atomicMin merging
    hipMemsetAsync(d_out, 0x7f, (size_t)B_ * N_ * sizeof(float), stream);
    hipLaunchKernelGGL(shapelet_min_kernel, dim3(512), dim3(THREADS), 0, stream,
                       x, shp, (float*)d_out);
}